// Round 4
// baseline (142.328 us; speedup 1.0000x reference)
//
#include <hip/hip_runtime.h>
#include <math.h>

#define N 512
#define NB 32
#define NC 16
#define CH 20
#define JP 4                   // j parts (128 j's each)
#define NUNITS (32 * 8 * JP)   // 1024 blocks for k2

// ws layout (floats):
//   h      : N*CH  = 10240  @ 0
//   M      : N*N   = 262144 @ 10240
//   s      : N     = 512    @ 272384  (W3-weighted o-dot, atomic)
//   osum32 : 32             @ 272896  (per-b o totals, atomic)
//   counter: 1 int          @ 272928
#define WS_H 0
#define WS_M 10240
#define WS_S 272384
#define WS_OSUM 272896
#define WS_CNT 272928

__global__ __launch_bounds__(128) void k1_fwd(
        const float* __restrict__ x,
        const float* __restrict__ W1, const float* __restrict__ b1,
        const float* __restrict__ W2, const float* __restrict__ b2,
        const float* __restrict__ T,
        float* __restrict__ h_g, float* __restrict__ M_g,
        float* __restrict__ s_g, float* __restrict__ osum32,
        int* __restrict__ counter)
{
    const int i = blockIdx.x;
    const int t = threadIdx.x;
    __shared__ float xs[CH];
    __shared__ float h1s[128];
    __shared__ float hs[CH];

    if (t == 0) s_g[i] = 0.f;            // k2 (stream-ordered after k1) atomics into these
    if (i == 0) {
        if (t < NB) osum32[t] = 0.f;
        if (t == 0) *counter = 0;
    }
    if (t < CH) xs[t] = x[i * CH + t];
    __syncthreads();

    // fc1: h1[t] = relu(b1[t] + x . W1[:,t]), W1 is (20,128) row-major
    float a = b1[t];
    #pragma unroll
    for (int k = 0; k < CH; ++k) a += xs[k] * W1[k * 128 + t];
    h1s[t] = fmaxf(a, 0.f);
    __syncthreads();

    // fc2: h[t] = relu(b2[t] + h1 . W2[:,t]), W2 is (128,20) row-major
    if (t < CH) {
        float a2 = b2[t];
        #pragma unroll 16
        for (int k = 0; k < 128; ++k) a2 += h1s[k] * W2[k * CH + t];
        a2 = fmaxf(a2, 0.f);
        hs[t] = a2;
        h_g[i * CH + t] = a2;
    }
    __syncthreads();

    // M[i,:] = h . T, T is (20,512) row-major
    #pragma unroll
    for (int r = 0; r < 4; ++r) {
        const int m = t + r * 128;
        float a3 = 0.f;
        #pragma unroll
        for (int k = 0; k < CH; ++k) a3 += hs[k] * T[k * N + m];
        M_g[i * N + m] = a3;
    }
}

// Grid: 1024 units = (b=32) x (ic=8: 64 i's) x (jp=4: 128 j's), 256 thr.
// Lane owns one i; wave owns a 32-j subrange; inner reads of the j-slice are
// wave-uniform LDS broadcasts. Output folded through W3 immediately:
//   s[i]     += W3[20+b] * o_part(i,b,jp)   (atomic)
//   osum32[b] += sum_i o_part(i,b,jp)        (atomic, for the mean)
// Last block to finish runs the k3 epilogue (all comms via device atomics).
__global__ __launch_bounds__(256) void k2_odist(
        const float* __restrict__ M_g, const float* __restrict__ h_g,
        const float* __restrict__ W3, const float* __restrict__ b3,
        float* __restrict__ s_g, float* __restrict__ osum32,
        int* __restrict__ counter, float* __restrict__ out)
{
    const int t = threadIdx.x;
    const int unit = blockIdx.x;
    const int b  = unit & 31;
    const int ic = (unit >> 5) & 7;
    const int jp = unit >> 8;

    __shared__ __align__(16) float sj[128][NC];  // 8 KB j-slice
    __shared__ float red[4][64];
    __shared__ int last;
    __shared__ float smean;

    // stage 128 j-rows x 16 floats: 2 threads per row (8 floats each)
    {
        const int row = t >> 1, half = t & 1;
        const float4* src = reinterpret_cast<const float4*>(
            M_g + (size_t)(jp * 128 + row) * N + b * NC + half * 8);
        float4 v0 = src[0], v1 = src[1];
        float4* dst = reinterpret_cast<float4*>(&sj[row][half * 8]);
        dst[0] = v0; dst[1] = v1;
    }

    // this lane's Mi slice (16 floats) in registers
    const int lane = t & 63;
    const int w = t >> 6;
    const int i = ic * 64 + lane;
    float mi[NC];
    {
        const float4* src = reinterpret_cast<const float4*>(M_g + (size_t)i * N + b * NC);
        float4 a0 = src[0], a1 = src[1], a2 = src[2], a3 = src[3];
        mi[0]=a0.x; mi[1]=a0.y; mi[2]=a0.z; mi[3]=a0.w;
        mi[4]=a1.x; mi[5]=a1.y; mi[6]=a1.z; mi[7]=a1.w;
        mi[8]=a2.x; mi[9]=a2.y; mi[10]=a2.z; mi[11]=a2.w;
        mi[12]=a3.x; mi[13]=a3.y; mi[14]=a3.z; mi[15]=a3.w;
    }
    __syncthreads();

    float acc = 0.f;
    #pragma unroll 4
    for (int jl = 0; jl < 32; ++jl) {
        const float* s = sj[w * 32 + jl];   // wave-uniform -> LDS broadcast
        float d0 = 0.f, d1 = 0.f, d2 = 0.f, d3 = 0.f;
        #pragma unroll
        for (int c = 0; c < NC; c += 4) {
            d0 += fabsf(mi[c + 0] - s[c + 0]);
            d1 += fabsf(mi[c + 1] - s[c + 1]);
            d2 += fabsf(mi[c + 2] - s[c + 2]);
            d3 += fabsf(mi[c + 3] - s[c + 3]);
        }
        acc += __expf(-((d0 + d1) + (d2 + d3)));
    }

    red[w][lane] = acc;
    __syncthreads();
    if (t < 64) {
        const float s4 = red[0][t] + red[1][t] + red[2][t] + red[3][t];
        atomicAdd(&s_g[ic * 64 + t], s4 * W3[CH + b]);
        float v = s4;
        #pragma unroll
        for (int off = 32; off > 0; off >>= 1) v += __shfl_down(v, off, 64);
        if (t == 0) atomicAdd(&osum32[b], v);
    }

    // ---- arrival: last block runs the epilogue ----
    __threadfence();
    if (t == 0) {
        const int old = atomicAdd(counter, 1);
        last = (old == NUNITS - 1) ? 1 : 0;
    }
    __syncthreads();
    if (!last) return;

    // mean of o: read the 32 per-b totals via atomic RMW (coherent)
    float v = 0.f;
    if (t < NB) v = atomicAdd(&osum32[t], 0.f);
    if (t < 64) {
        #pragma unroll
        for (int off = 16; off > 0; off >>= 1) v += __shfl_down(v, off, 64);
        if (t == 0) smean = v * (1.f / (float)(N * NB));
    }
    __syncthreads();
    const float mean = smean;

    float w3sum = 0.f;
    #pragma unroll
    for (int bb = 0; bb < NB; ++bb) w3sum += W3[CH + bb];

    #pragma unroll
    for (int r = 0; r < 2; ++r) {
        const int ii = t + r * 256;
        const float sv = atomicAdd(&s_g[ii], 0.f);   // coherent read
        float a = b3[0] + sv - mean * w3sum;
        #pragma unroll
        for (int k = 0; k < CH; ++k) a += h_g[ii * CH + k] * W3[k];
        out[ii] = 1.f / (1.f + __expf(-a));
    }
}

extern "C" void kernel_launch(void* const* d_in, const int* in_sizes, int n_in,
                              void* d_out, int out_size, void* d_ws, size_t ws_size,
                              hipStream_t stream) {
    const float* x  = (const float*)d_in[0];
    const float* W1 = (const float*)d_in[1];
    const float* b1 = (const float*)d_in[2];
    const float* W2 = (const float*)d_in[3];
    const float* b2 = (const float*)d_in[4];
    const float* T  = (const float*)d_in[5];
    const float* W3 = (const float*)d_in[6];
    const float* b3 = (const float*)d_in[7];
    float* out = (float*)d_out;

    float* ws     = (float*)d_ws;
    float* h_g    = ws + WS_H;
    float* M_g    = ws + WS_M;
    float* s_g    = ws + WS_S;
    float* osum32 = ws + WS_OSUM;
    int*   counter = (int*)(ws + WS_CNT);

    k1_fwd<<<N, 128, 0, stream>>>(x, W1, b1, W2, b2, T, h_g, M_g, s_g, osum32, counter);
    k2_odist<<<NUNITS, 256, 0, stream>>>(M_g, h_g, W3, b3, s_g, osum32, counter, out);
}

// Round 5
// 93.056 us; speedup vs baseline: 1.5295x; 1.5295x over previous
//
#include <hip/hip_runtime.h>
#include <math.h>

#define N 512
#define NB 32
#define NC 16
#define CH 20
#define JP 4                   // j parts (128 j's each)
#define NUNITS (32 * 8 * JP)   // 1024 blocks for k2

// ws layout (floats):
//   h      : N*CH  = 10240  @ 0
//   M      : N*N   = 262144 @ 10240
//   s      : N     = 512    @ 272384  (W3-weighted o-dot, atomic)
//   osum32 : 32             @ 272896  (per-b o totals, atomic)
//   counter: 1 int          @ 272928
#define WS_H 0
#define WS_M 10240
#define WS_S 272384
#define WS_OSUM 272896
#define WS_CNT 272928

__global__ __launch_bounds__(128) void k1_fwd(
        const float* __restrict__ x,
        const float* __restrict__ W1, const float* __restrict__ b1,
        const float* __restrict__ W2, const float* __restrict__ b2,
        const float* __restrict__ T,
        float* __restrict__ h_g, float* __restrict__ M_g,
        float* __restrict__ s_g, float* __restrict__ osum32,
        int* __restrict__ counter)
{
    const int i = blockIdx.x;
    const int t = threadIdx.x;
    __shared__ float xs[CH];
    __shared__ float h1s[128];
    __shared__ float hs[CH];

    if (t == 0) s_g[i] = 0.f;            // k2 (stream-ordered after k1) atomics into these
    if (i == 0) {
        if (t < NB) osum32[t] = 0.f;
        if (t == 0) *counter = 0;
    }
    if (t < CH) xs[t] = x[i * CH + t];
    __syncthreads();

    // fc1: h1[t] = relu(b1[t] + x . W1[:,t]), W1 is (20,128) row-major
    float a = b1[t];
    #pragma unroll
    for (int k = 0; k < CH; ++k) a += xs[k] * W1[k * 128 + t];
    h1s[t] = fmaxf(a, 0.f);
    __syncthreads();

    // fc2: h[t] = relu(b2[t] + h1 . W2[:,t]), W2 is (128,20) row-major
    if (t < CH) {
        float a2 = b2[t];
        #pragma unroll 16
        for (int k = 0; k < 128; ++k) a2 += h1s[k] * W2[k * CH + t];
        a2 = fmaxf(a2, 0.f);
        hs[t] = a2;
        h_g[i * CH + t] = a2;
    }
    __syncthreads();

    // M[i,:] = h . T, T is (20,512) row-major
    #pragma unroll
    for (int r = 0; r < 4; ++r) {
        const int m = t + r * 128;
        float a3 = 0.f;
        #pragma unroll
        for (int k = 0; k < CH; ++k) a3 += hs[k] * T[k * N + m];
        M_g[i * N + m] = a3;
    }
}

// Grid: 1024 units = (b=32) x (ic=8: 64 i's) x (jp=4: 128 j's), 256 thr.
// Lane owns one i; wave owns a 32-j subrange; inner reads of the j-slice are
// wave-uniform LDS float4 broadcasts. Output folded through W3 immediately:
//   s[i]      += W3[20+b] * o_part(i,b,jp)   (atomic)
//   osum32[b] += sum_i o_part(i,b,jp)        (atomic, for the mean)
// Last block runs the epilogue. Release = s_waitcnt vmcnt(0) (atomics have
// completed at the coherent point) — NOT __threadfence() (whose L2 writeback
// cost ~35us across 1024 blocks in round 4).
__global__ __launch_bounds__(256) void k2_odist(
        const float* __restrict__ M_g, const float* __restrict__ h_g,
        const float* __restrict__ W3, const float* __restrict__ b3,
        float* __restrict__ s_g, float* __restrict__ osum32,
        int* __restrict__ counter, float* __restrict__ out)
{
    const int t = threadIdx.x;
    const int unit = blockIdx.x;
    const int b  = unit & 31;
    const int ic = (unit >> 5) & 7;
    const int jp = unit >> 8;

    __shared__ __align__(16) float sj[128][NC];  // 8 KB j-slice
    __shared__ float red[4][64];
    __shared__ int last;
    __shared__ float smean;

    // stage 128 j-rows x 16 floats: 2 threads per row (8 floats each)
    {
        const int row = t >> 1, half = t & 1;
        const float4* src = reinterpret_cast<const float4*>(
            M_g + (size_t)(jp * 128 + row) * N + b * NC + half * 8);
        float4 v0 = src[0], v1 = src[1];
        float4* dst = reinterpret_cast<float4*>(&sj[row][half * 8]);
        dst[0] = v0; dst[1] = v1;
    }

    // this lane's Mi slice (16 floats) in registers
    const int lane = t & 63;
    const int w = t >> 6;
    const int i = ic * 64 + lane;
    float mi[NC];
    {
        const float4* src = reinterpret_cast<const float4*>(M_g + (size_t)i * N + b * NC);
        float4 a0 = src[0], a1 = src[1], a2 = src[2], a3 = src[3];
        mi[0]=a0.x; mi[1]=a0.y; mi[2]=a0.z; mi[3]=a0.w;
        mi[4]=a1.x; mi[5]=a1.y; mi[6]=a1.z; mi[7]=a1.w;
        mi[8]=a2.x; mi[9]=a2.y; mi[10]=a2.z; mi[11]=a2.w;
        mi[12]=a3.x; mi[13]=a3.y; mi[14]=a3.z; mi[15]=a3.w;
    }
    __syncthreads();

    float acc = 0.f;
    #pragma unroll 4
    for (int jl = 0; jl < 32; ++jl) {
        const float4* s4v = reinterpret_cast<const float4*>(sj[w * 32 + jl]); // wave-uniform
        const float4 s0 = s4v[0], s1 = s4v[1], s2 = s4v[2], s3 = s4v[3];      // 4x ds_read_b128
        float d0 = fabsf(mi[0]  - s0.x) + fabsf(mi[4]  - s1.x)
                 + fabsf(mi[8]  - s2.x) + fabsf(mi[12] - s3.x);
        float d1 = fabsf(mi[1]  - s0.y) + fabsf(mi[5]  - s1.y)
                 + fabsf(mi[9]  - s2.y) + fabsf(mi[13] - s3.y);
        float d2 = fabsf(mi[2]  - s0.z) + fabsf(mi[6]  - s1.z)
                 + fabsf(mi[10] - s2.z) + fabsf(mi[14] - s3.z);
        float d3 = fabsf(mi[3]  - s0.w) + fabsf(mi[7]  - s1.w)
                 + fabsf(mi[11] - s2.w) + fabsf(mi[15] - s3.w);
        acc += __expf(-((d0 + d1) + (d2 + d3)));
    }

    red[w][lane] = acc;
    __syncthreads();
    if (t < 64) {
        const float s4 = red[0][t] + red[1][t] + red[2][t] + red[3][t];
        atomicAdd(&s_g[ic * 64 + t], s4 * W3[CH + b]);
        float v = s4;
        #pragma unroll
        for (int off = 32; off > 0; off >>= 1) v += __shfl_down(v, off, 64);
        if (t == 0) atomicAdd(&osum32[b], v);
    }

    // ---- arrival: wait for OUR atomics to complete (coherent point), then count.
    asm volatile("s_waitcnt vmcnt(0)" ::: "memory");
    if (t == 0) {
        const int old = atomicAdd(counter, 1);
        last = (old == NUNITS - 1) ? 1 : 0;
    }
    __syncthreads();
    if (!last) return;

    // mean of o: read the 32 per-b totals via atomic RMW (coherent)
    float v = 0.f;
    if (t < NB) v = atomicAdd(&osum32[t], 0.f);
    if (t < 64) {
        #pragma unroll
        for (int off = 16; off > 0; off >>= 1) v += __shfl_down(v, off, 64);
        if (t == 0) smean = v * (1.f / (float)(N * NB));
    }
    __syncthreads();
    const float mean = smean;

    float w3sum = 0.f;
    #pragma unroll
    for (int bb = 0; bb < NB; ++bb) w3sum += W3[CH + bb];

    #pragma unroll
    for (int r = 0; r < 2; ++r) {
        const int ii = t + r * 256;
        const float sv = atomicAdd(&s_g[ii], 0.f);   // coherent read
        float a = b3[0] + sv - mean * w3sum;
        #pragma unroll
        for (int k = 0; k < CH; ++k) a += h_g[ii * CH + k] * W3[k];
        out[ii] = 1.f / (1.f + __expf(-a));
    }
}

extern "C" void kernel_launch(void* const* d_in, const int* in_sizes, int n_in,
                              void* d_out, int out_size, void* d_ws, size_t ws_size,
                              hipStream_t stream) {
    const float* x  = (const float*)d_in[0];
    const float* W1 = (const float*)d_in[1];
    const float* b1 = (const float*)d_in[2];
    const float* W2 = (const float*)d_in[3];
    const float* b2 = (const float*)d_in[4];
    const float* T  = (const float*)d_in[5];
    const float* W3 = (const float*)d_in[6];
    const float* b3 = (const float*)d_in[7];
    float* out = (float*)d_out;

    float* ws     = (float*)d_ws;
    float* h_g    = ws + WS_H;
    float* M_g    = ws + WS_M;
    float* s_g    = ws + WS_S;
    float* osum32 = ws + WS_OSUM;
    int*   counter = (int*)(ws + WS_CNT);

    k1_fwd<<<N, 128, 0, stream>>>(x, W1, b1, W2, b2, T, h_g, M_g, s_g, osum32, counter);
    k2_odist<<<NUNITS, 256, 0, stream>>>(M_g, h_g, W3, b3, s_g, osum32, counter, out);
}

// Round 6
// 85.526 us; speedup vs baseline: 1.6641x; 1.0880x over previous
//
#include <hip/hip_runtime.h>
#include <math.h>

#define N 512
#define NB 32
#define NC 16
#define CH 20
#define JP 4                   // j parts (128 j's each)
#define NUNITS (32 * 8 * JP)   // 1024 blocks for k2

// ws layout (floats):
//   M      : N*N = 262144 @ 0
//   s      : N   = 512    @ 262144  (b3 + h.W3 init, then W3-weighted o-dot atomics)
//   osum32 : 32           @ 262656  (per-b o totals, atomic)
#define WS_M 0
#define WS_S 262144
#define WS_OSUM 262656

__global__ __launch_bounds__(128) void k1_fwd(
        const float* __restrict__ x,
        const float* __restrict__ W1, const float* __restrict__ b1,
        const float* __restrict__ W2, const float* __restrict__ b2,
        const float* __restrict__ T,
        const float* __restrict__ W3, const float* __restrict__ b3,
        float* __restrict__ M_g, float* __restrict__ s_g,
        float* __restrict__ osum32)
{
    const int i = blockIdx.x;
    const int t = threadIdx.x;
    __shared__ float xs[CH];
    __shared__ float h1s[128];
    __shared__ float hs[CH];

    if (i == 0 && t < NB) osum32[t] = 0.f;   // k2 is stream-ordered after k1
    if (t < CH) xs[t] = x[i * CH + t];
    __syncthreads();

    // fc1: h1[t] = relu(b1[t] + x . W1[:,t]), W1 is (20,128) row-major
    float a = b1[t];
    #pragma unroll
    for (int k = 0; k < CH; ++k) a += xs[k] * W1[k * 128 + t];
    h1s[t] = fmaxf(a, 0.f);
    __syncthreads();

    // fc2: h[t] = relu(b2[t] + h1 . W2[:,t]), W2 is (128,20) row-major
    float a2 = 0.f;
    if (t < CH) {
        a2 = b2[t];
        #pragma unroll 16
        for (int k = 0; k < 128; ++k) a2 += h1s[k] * W2[k * CH + t];
        a2 = fmaxf(a2, 0.f);
        hs[t] = a2;
    }

    // s_g[i] = b3 + h . W3[0:20]  (wave-0 shuffle reduce; lanes >=20 carry 0)
    if (t < 64) {
        float p = (t < CH) ? a2 * W3[t] : 0.f;
        #pragma unroll
        for (int off = 32; off > 0; off >>= 1) p += __shfl_down(p, off, 64);
        if (t == 0) s_g[i] = p + b3[0];
    }
    __syncthreads();

    // M[i,:] = h . T, T is (20,512) row-major
    #pragma unroll
    for (int r = 0; r < 4; ++r) {
        const int m = t + r * 128;
        float a3 = 0.f;
        #pragma unroll
        for (int k = 0; k < CH; ++k) a3 += hs[k] * T[k * N + m];
        M_g[i * N + m] = a3;
    }
}

// Grid: 1024 units = (b=32) x (ic=8: 64 i's) x (jp=4: 128 j's), 256 thr.
// Lane owns one i; wave owns a 32-j subrange; inner reads of the j-slice are
// wave-uniform LDS float4 broadcasts (conflict-free). Output folded through
// W3 immediately:
//   s[i]      += W3[20+b] * o_part(i,b,jp)   (atomic)
//   osum32[b] += sum_i o_part(i,b,jp)        (atomic, for the mean)
__global__ __launch_bounds__(256) void k2_odist(
        const float* __restrict__ M_g, const float* __restrict__ W3,
        float* __restrict__ s_g, float* __restrict__ osum32)
{
    const int t = threadIdx.x;
    const int unit = blockIdx.x;
    const int b  = unit & 31;
    const int ic = (unit >> 5) & 7;
    const int jp = unit >> 8;

    __shared__ __align__(16) float sj[128][NC];  // 8 KB j-slice
    __shared__ float red[4][64];

    // stage 128 j-rows x 16 floats: 2 threads per row (8 floats each)
    {
        const int row = t >> 1, half = t & 1;
        const float4* src = reinterpret_cast<const float4*>(
            M_g + (size_t)(jp * 128 + row) * N + b * NC + half * 8);
        float4 v0 = src[0], v1 = src[1];
        float4* dst = reinterpret_cast<float4*>(&sj[row][half * 8]);
        dst[0] = v0; dst[1] = v1;
    }

    // this lane's Mi slice (16 floats) in registers
    const int lane = t & 63;
    const int w = t >> 6;
    const int i = ic * 64 + lane;
    float mi[NC];
    {
        const float4* src = reinterpret_cast<const float4*>(M_g + (size_t)i * N + b * NC);
        float4 a0 = src[0], a1 = src[1], a2 = src[2], a3 = src[3];
        mi[0]=a0.x; mi[1]=a0.y; mi[2]=a0.z; mi[3]=a0.w;
        mi[4]=a1.x; mi[5]=a1.y; mi[6]=a1.z; mi[7]=a1.w;
        mi[8]=a2.x; mi[9]=a2.y; mi[10]=a2.z; mi[11]=a2.w;
        mi[12]=a3.x; mi[13]=a3.y; mi[14]=a3.z; mi[15]=a3.w;
    }
    __syncthreads();

    float acc = 0.f;
    #pragma unroll 4
    for (int jl = 0; jl < 32; ++jl) {
        const float4* s4v = reinterpret_cast<const float4*>(sj[w * 32 + jl]); // wave-uniform
        const float4 s0 = s4v[0], s1 = s4v[1], s2 = s4v[2], s3 = s4v[3];      // 4x ds_read_b128
        float d0 = fabsf(mi[0]  - s0.x) + fabsf(mi[4]  - s1.x)
                 + fabsf(mi[8]  - s2.x) + fabsf(mi[12] - s3.x);
        float d1 = fabsf(mi[1]  - s0.y) + fabsf(mi[5]  - s1.y)
                 + fabsf(mi[9]  - s2.y) + fabsf(mi[13] - s3.y);
        float d2 = fabsf(mi[2]  - s0.z) + fabsf(mi[6]  - s1.z)
                 + fabsf(mi[10] - s2.z) + fabsf(mi[14] - s3.z);
        float d3 = fabsf(mi[3]  - s0.w) + fabsf(mi[7]  - s1.w)
                 + fabsf(mi[11] - s2.w) + fabsf(mi[15] - s3.w);
        acc += __expf(-((d0 + d1) + (d2 + d3)));
    }

    red[w][lane] = acc;
    __syncthreads();
    if (t < 64) {
        const float s4 = red[0][t] + red[1][t] + red[2][t] + red[3][t];
        atomicAdd(&s_g[ic * 64 + t], s4 * W3[CH + b]);
        float v = s4;
        #pragma unroll
        for (int off = 32; off > 0; off >>= 1) v += __shfl_down(v, off, 64);
        if (t == 0) atomicAdd(&osum32[b], v);
    }
}

__global__ __launch_bounds__(512) void k3_final(
        const float* __restrict__ s_g, const float* __restrict__ osum32,
        const float* __restrict__ W3, float* __restrict__ out)
{
    const int t = threadIdx.x;    // 0..511, single block
    __shared__ float smean;

    if (t < 64) {
        float v = (t < NB) ? osum32[t] : 0.f;
        #pragma unroll
        for (int off = 32; off > 0; off >>= 1) v += __shfl_down(v, off, 64);
        if (t == 0) smean = v * (1.f / (float)(N * NB));
    }
    __syncthreads();

    float w3sum = 0.f;            // uniform scalar loads
    #pragma unroll
    for (int b = 0; b < NB; ++b) w3sum += W3[CH + b];

    const float a = s_g[t] - smean * w3sum;
    out[t] = 1.f / (1.f + __expf(-a));
}

extern "C" void kernel_launch(void* const* d_in, const int* in_sizes, int n_in,
                              void* d_out, int out_size, void* d_ws, size_t ws_size,
                              hipStream_t stream) {
    const float* x  = (const float*)d_in[0];
    const float* W1 = (const float*)d_in[1];
    const float* b1 = (const float*)d_in[2];
    const float* W2 = (const float*)d_in[3];
    const float* b2 = (const float*)d_in[4];
    const float* T  = (const float*)d_in[5];
    const float* W3 = (const float*)d_in[6];
    const float* b3 = (const float*)d_in[7];
    float* out = (float*)d_out;

    float* ws     = (float*)d_ws;
    float* M_g    = ws + WS_M;
    float* s_g    = ws + WS_S;
    float* osum32 = ws + WS_OSUM;

    k1_fwd<<<N, 128, 0, stream>>>(x, W1, b1, W2, b2, T, W3, b3, M_g, s_g, osum32);
    k2_odist<<<NUNITS, 256, 0, stream>>>(M_g, W3, s_g, osum32);
    k3_final<<<1, 512, 0, stream>>>(s_g, osum32, W3, out);
}